// Round 17
// baseline (497.075 us; speedup 1.0000x reference)
//
#include <hip/hip_runtime.h>
#include <math.h>

#define BN 32
#define NP 1024
#define KNN 30
#define NR 64
#define NFPS 55

// s = dinv*dinv with dinv = 1/sqrt(30) in f32, matching the reference's
// normalized laplacian (every kNN row-sum is exactly 30).
__device__ __forceinline__ float lap_s() {
    const float dv = 1.0f / sqrtf(30.0f);
    return dv * dv;
}

// Distance with ALL operations IEEE-pinned (contract off): guarantees the
// phase-A value and the phase-C recompute are bit-identical.
__device__ __forceinline__ float dist7(const float4& xiA, const float4& xiB,
                                       float sqi, const float4& ca, const float4& cb) {
#pragma clang fp contract(off)
    float dot = xiA.x * ca.x;
    dot = fmaf(xiA.y, ca.y, dot);
    dot = fmaf(xiA.z, ca.z, dot);
    dot = fmaf(xiA.w, ca.w, dot);
    dot = fmaf(xiB.x, cb.x, dot);
    dot = fmaf(xiB.y, cb.y, dot);
    dot = fmaf(xiB.z, cb.z, dot);
    float r = sqi + cb.w;
    r = r - 2.f * dot;
    return fmaxf(r, 0.f);
}

// ---------------------------------------------------------------------------
// k_knn: 4 waves/row-group split over j, med3 value-only top-30 per wave
// (4-wide j-chunks), per-row 4-way VALUE merge (tie -> lowest wave = jax
// (dist,idx) order), per-wave threshold rescan emits its taken_w indices in
// ascending j (set semantics). xs1 fused via per-wave partials. Block (0,0)
// also does the reg-init work.
// ---------------------------------------------------------------------------
__global__ __launch_bounds__(256) void k_knn(const float* __restrict__ x,
                                             int* __restrict__ knn,
                                             float* __restrict__ xs1,
                                             const float* __restrict__ fc1_w,
                                             const float* __restrict__ fc1_b,
                                             const float* __restrict__ fc3_w,
                                             const float* __restrict__ fc3_b,
                                             float* __restrict__ regs) {
    __shared__ float xls[NP * 8];          // 32768 B: 7 feats + sq in slot 7
    __shared__ float vals[4 * KNN * 64];   // 30720 B (overlaid: init red / ns)
    __shared__ float Tm[4 * 64];           // per-(wave,row) threshold
    __shared__ int   Pk[4 * 64];           // base | (need<<8) | (tk<<16)
    int b = blockIdx.x;
    int t = threadIdx.x;
    int ln = t & 63, wv = t >> 6;

    // ---- folded k_init (one block; uniform branch so barriers are legal) ----
    if (b == 0 && blockIdx.y == 0) {
        float* r1 = vals;        // overlay (vals not yet used)
        float* r2 = vals + 256;
        float s1 = 0.f;
        for (int i = t; i < 512; i += 256) { float v = fc1_w[(size_t)i * 256]; s1 += v * v; }
        float v2 = fc3_w[(size_t)t * 40];
        r1[t] = s1; r2[t] = v2 * v2;
        __syncthreads();
        for (int st = 128; st > 0; st >>= 1) {
            if (t < st) { r1[t] += r1[t + st]; r2[t] += r2[t + st]; }
            __syncthreads();
        }
        if (t == 0) {
            regs[0] = 0.f; regs[1] = 0.f; regs[2] = 0.f;
            regs[3] = r1[0];
            regs[4] = fc1_b[0] * fc1_b[0];
            regs[5] = r2[0];
            regs[6] = fc3_b[0] * fc3_b[0];
        }
        __syncthreads();
    }

    const float* xb = x + (size_t)b * NP * 7;
    for (int q = t; q < NP * 8; q += 256) {
        int r = q >> 3, d = q & 7;
        xls[q] = (d < 7) ? xb[r * 7 + d] : 0.f;
    }
    __syncthreads();
    for (int r = t; r < NP; r += 256) {
        float s = 0.f;
#pragma unroll
        for (int d = 0; d < 7; ++d) { float v = xls[r * 8 + d]; s += v * v; }
        xls[r * 8 + 7] = s;
    }
    __syncthreads();

    int grow = blockIdx.y * 64 + ln;
    float4 xiA = *(const float4*)&xls[grow * 8];
    float4 xiB = *(const float4*)&xls[grow * 8 + 4];
    float sqi = xiB.w;

    // ---- phase A: wave-local branchless value top-30, 4-wide j chunks ----
    float bd[KNN];
#pragma unroll
    for (int q = 0; q < KNN; ++q) bd[q] = __builtin_inff();
    int jbase = wv * 256;
    for (int jc = 0; jc < 256; jc += 4) {
        const float* p = &xls[(jbase + jc) * 8];
        float4 a0 = *(const float4*)(p +  0), b0 = *(const float4*)(p +  4);
        float4 a1 = *(const float4*)(p +  8), b1 = *(const float4*)(p + 12);
        float4 a2 = *(const float4*)(p + 16), b2 = *(const float4*)(p + 20);
        float4 a3 = *(const float4*)(p + 24), b3 = *(const float4*)(p + 28);
        float d0 = dist7(xiA, xiB, sqi, a0, b0);
        float d1 = dist7(xiA, xiB, sqi, a1, b1);
        float d2 = dist7(xiA, xiB, sqi, a2, b2);
        float d3 = dist7(xiA, xiB, sqi, a3, b3);
#pragma unroll
        for (int q = KNN - 1; q >= 1; --q) bd[q] = __builtin_amdgcn_fmed3f(bd[q - 1], d0, bd[q]);
        bd[0] = fminf(bd[0], d0);
#pragma unroll
        for (int q = KNN - 1; q >= 1; --q) bd[q] = __builtin_amdgcn_fmed3f(bd[q - 1], d1, bd[q]);
        bd[0] = fminf(bd[0], d1);
#pragma unroll
        for (int q = KNN - 1; q >= 1; --q) bd[q] = __builtin_amdgcn_fmed3f(bd[q - 1], d2, bd[q]);
        bd[0] = fminf(bd[0], d2);
#pragma unroll
        for (int q = KNN - 1; q >= 1; --q) bd[q] = __builtin_amdgcn_fmed3f(bd[q - 1], d3, bd[q]);
        bd[0] = fminf(bd[0], d3);
    }
#pragma unroll
    for (int q = 0; q < KNN; ++q) vals[wv * (KNN * 64) + q * 64 + ln] = bd[q];
    __syncthreads();

    // ---- merge: one thread per row, 4-way value merge, tie -> lowest wave ----
    if (t < 64) {
        const float inf = __builtin_inff();
        float h0 = vals[0 * 1920 + t];
        float h1 = vals[1 * 1920 + t];
        float h2 = vals[2 * 1920 + t];
        float h3 = vals[3 * 1920 + t];
        int p0 = 0, p1 = 0, p2 = 0, p3 = 0;
        for (int s = 0; s < KNN; ++s) {
            float best = h0; int bw = 0;
            if (h1 < best) { best = h1; bw = 1; }
            if (h2 < best) { best = h2; bw = 2; }
            if (h3 < best) { best = h3; bw = 3; }
            if (bw == 0)      { ++p0; h0 = (p0 < KNN) ? vals[0 * 1920 + p0 * 64 + t] : inf; }
            else if (bw == 1) { ++p1; h1 = (p1 < KNN) ? vals[1 * 1920 + p1 * 64 + t] : inf; }
            else if (bw == 2) { ++p2; h2 = (p2 < KNN) ? vals[2 * 1920 + p2 * 64 + t] : inf; }
            else              { ++p3; h3 = (p3 < KNN) ? vals[3 * 1920 + p3 * 64 + t] : inf; }
        }
        int bacc = 0;
        int tks[4] = {p0, p1, p2, p3};
#pragma unroll
        for (int w = 0; w < 4; ++w) {
            int tk = tks[w];
            float T; int need;
            if (tk == 0) { T = -__builtin_inff(); need = 0; }
            else {
                T = vals[w * 1920 + (tk - 1) * 64 + t];
                need = 1;
                for (int q = tk - 2; q >= 0; --q) {
                    if (vals[w * 1920 + q * 64 + t] == T) ++need; else break;
                }
            }
            Tm[w * 64 + t] = T;
            Pk[w * 64 + t] = bacc | (need << 8) | (tk << 16);
            bacc += tk;
        }
    }
    __syncthreads();

    // ---- phase C: per-wave threshold rescan (4-wide chunks), emit + ns ----
    float Tw = Tm[wv * 64 + ln];
    int pk = Pk[wv * 64 + ln];
    int base = pk & 255, need = (pk >> 8) & 255, tk = pk >> 16;
    int* kout = knn + ((size_t)b * NP + grow) * KNN;
    float n0 = 0.f, n1 = 0.f, n2 = 0.f, n3 = 0.f, n4 = 0.f, n5 = 0.f, n6 = 0.f;
    int cs = 0, ct = 0;
    for (int jc = 0; jc < 256; jc += 4) {
        const float* p = &xls[(jbase + jc) * 8];
        float4 a0 = *(const float4*)(p +  0), b0 = *(const float4*)(p +  4);
        float4 a1 = *(const float4*)(p +  8), b1 = *(const float4*)(p + 12);
        float4 a2 = *(const float4*)(p + 16), b2 = *(const float4*)(p + 20);
        float4 a3 = *(const float4*)(p + 24), b3 = *(const float4*)(p + 28);
        float d0 = dist7(xiA, xiB, sqi, a0, b0);
        float d1 = dist7(xiA, xiB, sqi, a1, b1);
        float d2 = dist7(xiA, xiB, sqi, a2, b2);
        float d3 = dist7(xiA, xiB, sqi, a3, b3);
#pragma unroll
        for (int u = 0; u < 4; ++u) {
            float dist = (u == 0) ? d0 : (u == 1) ? d1 : (u == 2) ? d2 : d3;
            const float4& ca = (u == 0) ? a0 : (u == 1) ? a1 : (u == 2) ? a2 : a3;
            const float4& cb = (u == 0) ? b0 : (u == 1) ? b1 : (u == 2) ? b2 : b3;
            bool lt = dist < Tw;
            bool eq = (dist == Tw) && (ct < need);
            if ((lt || eq) && (cs + ct < tk)) {
                kout[base + cs + ct] = jbase + jc + u;
                cs += lt ? 1 : 0;
                ct += eq ? 1 : 0;
                n0 += ca.x; n1 += ca.y; n2 += ca.z; n3 += ca.w;
                n4 += cb.x; n5 += cb.y; n6 += cb.z;
            }
        }
    }
    for (int q = cs + ct; q < tk; ++q) kout[base + q] = grow;  // safety net
    float* nsb = vals;
    nsb[wv * 448 + 0 * 64 + ln] = n0;
    nsb[wv * 448 + 1 * 64 + ln] = n1;
    nsb[wv * 448 + 2 * 64 + ln] = n2;
    nsb[wv * 448 + 3 * 64 + ln] = n3;
    nsb[wv * 448 + 4 * 64 + ln] = n4;
    nsb[wv * 448 + 5 * 64 + ln] = n5;
    nsb[wv * 448 + 6 * 64 + ln] = n6;
    __syncthreads();
    for (int u = t; u < 448; u += 256) {
        int d = u >> 6, rl = u & 63;
        float tot = nsb[d * 64 + rl] + nsb[448 + d * 64 + rl]
                  + nsb[896 + d * 64 + rl] + nsb[1344 + d * 64 + rl];
        int gr = blockIdx.y * 64 + rl;
        xs1[((size_t)b * NP + gr) * 7 + d] = xls[gr * 8 + d] - lap_s() * tot;
    }
}

// ---------------------------------------------------------------------------
// k_out: xs2 = 2 L xs1 - x, then out = relu([x|xs1|xs2] @ W1 + b1), (B,N,64).
// ---------------------------------------------------------------------------
__global__ __launch_bounds__(256) void k_out(const float* __restrict__ x,
                                             const float* __restrict__ xs1,
                                             const int* __restrict__ knn,
                                             const float* __restrict__ W1,
                                             const float* __restrict__ b1,
                                             float* __restrict__ out) {
    __shared__ float x1s[NP * 7];    // xs1 for ALL rows (neighbor gathers)
    __shared__ float x0s[128 * 7];   // x for this block's rows only
    __shared__ float fr[128 * 21];
    __shared__ float W1s[21 * 64];
    __shared__ float b1s[64];
    int b = blockIdx.x;
    int rbase = blockIdx.y * 128;
    int t = threadIdx.x;
    for (int q = t; q < NP * 7; q += 256) x1s[q] = xs1[(size_t)b * NP * 7 + q];
    for (int q = t; q < 128 * 7; q += 256) x0s[q] = x[(size_t)b * NP * 7 + (size_t)rbase * 7 + q];
    for (int q = t; q < 21 * 64; q += 256) W1s[q] = W1[q];
    if (t < 64) b1s[t] = b1[t];
    __syncthreads();
    if (t < 128) {
        int i = rbase + t;
        float f[21];
#pragma unroll
        for (int d = 0; d < 7; ++d) { f[d] = x0s[t * 7 + d]; f[7 + d] = x1s[i * 7 + d]; }
        float ns[7] = {0.f, 0.f, 0.f, 0.f, 0.f, 0.f, 0.f};
        const int* kn = knn + ((size_t)b * NP + i) * KNN;
        for (int q = 0; q < KNN; ++q) {
            int j = kn[q];
#pragma unroll
            for (int d = 0; d < 7; ++d) ns[d] += x1s[j * 7 + d];
        }
        const float s = lap_s();
#pragma unroll
        for (int d = 0; d < 7; ++d) f[14 + d] = 2.f * (f[7 + d] - s * ns[d]) - f[d];
#pragma unroll
        for (int d = 0; d < 21; ++d) fr[t * 21 + d] = f[d];
    }
    __syncthreads();
    int o = t & 63, g = t >> 6;
    for (int m = 0; m < 32; ++m) {
        int r = g * 32 + m;
        float acc = b1s[o];
#pragma unroll
        for (int d = 0; d < 21; ++d) acc += fr[r * 21 + d] * W1s[d * 64 + o];
        out[((size_t)b * NP + rbase + r) * 64 + o] = fmaxf(acc, 0.f);
    }
}

// ---------------------------------------------------------------------------
// k_z1v: fused Z1 = L@out gather + segment-max pools. Grid (B, 256+16+55):
//   y<256  -> Z1 rows y*4..y*4+3
//   y<272  -> V_reeb rows (y-256)*4.. (16-segment max)
//   else   -> V_fps row p=y-272 (1024-segment max)
// ---------------------------------------------------------------------------
__global__ __launch_bounds__(256) void k_z1v(const float* __restrict__ out,
                                             const int* __restrict__ knn,
                                             const int* __restrict__ sccs,
                                             const int* __restrict__ sccs_fps,
                                             float* __restrict__ Z1,
                                             float* __restrict__ Vr,
                                             float* __restrict__ Vf) {
    __shared__ int idxs[1024];
    __shared__ float red[256];
    int b = blockIdx.x, y = blockIdx.y;
    int t = threadIdx.x;
    const float* ob = out + (size_t)b * NP * 64;
    if (y < 256) {
        int i = y * 4 + (t >> 6);
        int f = t & 63;
        const int* kn = knn + ((size_t)b * NP + i) * KNN;
        float sum = 0.f;
        for (int q = 0; q < KNN; ++q) sum += ob[(size_t)kn[q] * 64 + f];
        Z1[((size_t)b * NP + i) * 64 + f] = ob[(size_t)i * 64 + f] - lap_s() * sum;
    } else if (y < 272) {
        int r = (y - 256) * 4 + (t >> 6);
        int f = t & 63;
        const int* sc = sccs + ((size_t)b * NR + r) * 16;
        float m = -__builtin_inff();
        for (int q = 0; q < 16; ++q) m = fmaxf(m, ob[(size_t)sc[q] * 64 + f]);
        Vr[((size_t)b * NR + r) * 64 + f] = m;
    } else {
        int p = y - 272;
        const int* sp = sccs_fps + ((size_t)b * NFPS + p) * 1024;
        for (int q = t; q < 1024; q += 256) idxs[q] = sp[q];
        __syncthreads();
        int f = t & 63, sc = t >> 6;
        float m = -__builtin_inff();
        for (int s = sc; s < 1024; s += 4) m = fmaxf(m, ob[(size_t)idxs[s] * 64 + f]);
        red[t] = m; __syncthreads();
        if (sc == 0) {
            m = fmaxf(fmaxf(red[f], red[64 + f]), fmaxf(red[128 + f], red[192 + f]));
            Vf[((size_t)b * NFPS + p) * 64 + f] = m;
        }
    }
}

// ---------------------------------------------------------------------------
// k_t1_lfps: fused (independent) narrow kernels. Grid (B, 3):
//   y<2  -> reg1 += sum((out^T Z1)^2) for f-half y (R10-proven t1 body;
//           do NOT widen -- the (B,8)/128-trip variant spilled to scratch)
//   y==2 -> L_fps build from V_fps (R10-proven lfps body)
// ---------------------------------------------------------------------------
__global__ __launch_bounds__(256) void k_t1_lfps(const float* __restrict__ out,
                                                 const float* __restrict__ Z1,
                                                 const float* __restrict__ Vfps,
                                                 float* __restrict__ regs,
                                                 float* __restrict__ Lf) {
    __shared__ float buf[8448];   // 33 KB union of both branches
    int b = blockIdx.x, y = blockIdx.y;
    int t = threadIdx.x;
    if (y < 2) {
        float* os = buf;              // 64*64
        float* zs = buf + 4096;       // 64*64
        float* red = buf + 8192;      // 256
        int f0 = y * 32;
        int fl = t >> 3;          // 0..31
        int gb = (t & 7) * 8;     // 0..56
        float acc[8];
#pragma unroll
        for (int q = 0; q < 8; ++q) acc[q] = 0.f;
        for (int c = 0; c < 16; ++c) {
            const float* ob = out + ((size_t)b * NP + c * 64) * 64;
            const float* zb = Z1 + ((size_t)b * NP + c * 64) * 64;
            for (int q = t; q < 64 * 64; q += 256) { os[q] = ob[q]; zs[q] = zb[q]; }
            __syncthreads();
            for (int n = 0; n < 64; ++n) {
                float a = os[n * 64 + f0 + fl];
#pragma unroll
                for (int q = 0; q < 8; ++q) acc[q] += a * zs[n * 64 + gb + q];
            }
            __syncthreads();
        }
        float loc = 0.f;
#pragma unroll
        for (int q = 0; q < 8; ++q) loc += acc[q] * acc[q];
        red[t] = loc; __syncthreads();
        for (int st = 128; st > 0; st >>= 1) { if (t < st) red[t] += red[t + st]; __syncthreads(); }
        if (t == 0) atomicAdd(&regs[0], red[0]);
    } else {
        float* Vs = buf;                    // 55*64 = 3520
        float* sq = buf + 3520;             // 55 (pad to 3584)
        float* dist = buf + 3584;           // 55*55 = 3025
        float* dinv = buf + 6609;           // 55
        for (int q = t; q < NFPS * 64; q += 256) Vs[q] = Vfps[(size_t)b * NFPS * 64 + q];
        __syncthreads();
        if (t < NFPS) {
            float s = 0.f;
            for (int f = 0; f < 64; ++f) { float v = Vs[t * 64 + f]; s += v * v; }
            sq[t] = s;
        }
        __syncthreads();
        for (int q = t; q < NFPS * NFPS; q += 256) {
            int i = q / NFPS, j = q % NFPS;
            float dot = 0.f;
            for (int f = 0; f < 64; ++f) dot += Vs[i * 64 + f] * Vs[j * 64 + f];
            dist[q] = fmaxf(sq[i] + sq[j] - 2.f * dot, 0.f);
        }
        __syncthreads();
        if (t < NFPS) {
            float s = 0.f;
            for (int j = 0; j < NFPS; ++j) s += dist[t * NFPS + j];
            dinv[t] = (s > 0.f) ? 1.0f / sqrtf(fmaxf(s, 1e-12f)) : 0.f;
        }
        __syncthreads();
        for (int q = t; q < NFPS * NFPS; q += 256) {
            int i = q / NFPS, j = q % NFPS;
            Lf[(size_t)b * NFPS * NFPS + q] = ((i == j) ? 1.f : 0.f) - dist[q] * dinv[i] * dinv[j];
        }
    }
}

// ---------------------------------------------------------------------------
// cheb_impl<N>: K=6 Chebyshev conv + relu + Z = L @ out, one batch, one
// 64-wide output-column slice. Register-tiled 4x4 per thread, float4 LDS
// reads both operands. Pad rows/cols zeroed so N=55 needs no read guards.
// ---------------------------------------------------------------------------
template<int N>
__device__ __forceinline__ void cheb_impl(const float* __restrict__ L,
                                          const float* __restrict__ V,
                                          const float* __restrict__ W,
                                          const float* __restrict__ bias,
                                          float* __restrict__ out,
                                          float* __restrict__ Z,
                                          float* Ls, float* bA, float* bB, float* Ws,
                                          int b, int sl) {
    constexpr int NPAD = (N + 3) & ~3;   // 64 or 56
    int t = threadIdx.x;
    int c0 = (t & 15) * 4;               // 0..60
    int r0 = (t >> 4) * 4;               // 0..60

    for (int q = t; q < 64 * 64; q += 256) { Ls[q] = 0.f; bA[q] = 0.f; bB[q] = 0.f; }
    __syncthreads();
    for (int q = t; q < N * N; q += 256) {
        int r = q / N, m = q % N;
        Ls[r * 64 + m] = L[(size_t)b * N * N + q];
    }
    for (int q = t; q < N * 64; q += 256) bA[q] = V[(size_t)b * N * 64 + q];
    {
        const float* Wk = W + sl * 64;
        for (int q = t; q < 64 * 64; q += 256) Ws[q] = Wk[(q >> 6) * 256 + (q & 63)];
    }
    float4 a4[4];
    {
        float4 bv = *(const float4*)&bias[sl * 64 + c0];
#pragma unroll
        for (int i = 0; i < 4; ++i) a4[i] = bv;
    }
    __syncthreads();

    auto accum = [&](const float* xb) {
        for (int m = 0; m < 64; m += 4) {
            float4 xv[4], wv[4];
#pragma unroll
            for (int i = 0; i < 4; ++i) xv[i] = *(const float4*)&xb[(r0 + i) * 64 + m];
#pragma unroll
            for (int mm = 0; mm < 4; ++mm) wv[mm] = *(const float4*)&Ws[(m + mm) * 64 + c0];
#pragma unroll
            for (int i = 0; i < 4; ++i) {
                float xi0 = xv[i].x, xi1 = xv[i].y, xi2 = xv[i].z, xi3 = xv[i].w;
                a4[i].x += xi0 * wv[0].x; a4[i].y += xi0 * wv[0].y; a4[i].z += xi0 * wv[0].z; a4[i].w += xi0 * wv[0].w;
                a4[i].x += xi1 * wv[1].x; a4[i].y += xi1 * wv[1].y; a4[i].z += xi1 * wv[1].z; a4[i].w += xi1 * wv[1].w;
                a4[i].x += xi2 * wv[2].x; a4[i].y += xi2 * wv[2].y; a4[i].z += xi2 * wv[2].z; a4[i].w += xi2 * wv[2].w;
                a4[i].x += xi3 * wv[3].x; a4[i].y += xi3 * wv[3].y; a4[i].z += xi3 * wv[3].z; a4[i].w += xi3 * wv[3].w;
            }
        }
    };
    auto chebmm = [&](const float* src, float* dst, bool first) {
        float4 acc[4];
#pragma unroll
        for (int i = 0; i < 4; ++i) acc[i] = make_float4(0.f, 0.f, 0.f, 0.f);
        for (int m = 0; m < NPAD; m += 4) {
            float4 sv[4], lv[4];
#pragma unroll
            for (int mm = 0; mm < 4; ++mm) sv[mm] = *(const float4*)&src[(m + mm) * 64 + c0];
#pragma unroll
            for (int i = 0; i < 4; ++i) lv[i] = *(const float4*)&Ls[(r0 + i) * 64 + m];
#pragma unroll
            for (int i = 0; i < 4; ++i) {
                float l0 = lv[i].x, l1 = lv[i].y, l2 = lv[i].z, l3 = lv[i].w;
                acc[i].x += l0 * sv[0].x; acc[i].y += l0 * sv[0].y; acc[i].z += l0 * sv[0].z; acc[i].w += l0 * sv[0].w;
                acc[i].x += l1 * sv[1].x; acc[i].y += l1 * sv[1].y; acc[i].z += l1 * sv[1].z; acc[i].w += l1 * sv[1].w;
                acc[i].x += l2 * sv[2].x; acc[i].y += l2 * sv[2].y; acc[i].z += l2 * sv[2].z; acc[i].w += l2 * sv[2].w;
                acc[i].x += l3 * sv[3].x; acc[i].y += l3 * sv[3].y; acc[i].z += l3 * sv[3].z; acc[i].w += l3 * sv[3].w;
            }
        }
#pragma unroll
        for (int i = 0; i < 4; ++i) {
            if (r0 + i < N) {
                float4* d = (float4*)&dst[(r0 + i) * 64 + c0];
                if (first) *d = acc[i];
                else {
                    float4 od = *d;
                    *d = make_float4(2.f * acc[i].x - od.x, 2.f * acc[i].y - od.y,
                                     2.f * acc[i].z - od.z, 2.f * acc[i].w - od.w);
                }
            }
        }
    };
    auto loadW = [&](int k) {
        const float* Wk = W + (size_t)k * 64 * 256 + sl * 64;
        for (int q = t; q < 64 * 64; q += 256) Ws[q] = Wk[(q >> 6) * 256 + (q & 63)];
    };

    accum(bA);                 __syncthreads();
    chebmm(bA, bB, true);      loadW(1);  __syncthreads();
    accum(bB);                 __syncthreads();
    chebmm(bB, bA, false);     loadW(2);  __syncthreads();
    accum(bA);                 __syncthreads();
    chebmm(bA, bB, false);     loadW(3);  __syncthreads();
    accum(bB);                 __syncthreads();
    chebmm(bB, bA, false);     loadW(4);  __syncthreads();
    accum(bA);                 __syncthreads();
    chebmm(bA, bB, false);     loadW(5);  __syncthreads();
    accum(bB);                 __syncthreads();

    float* ob = out + (size_t)b * N * 256 + sl * 64;
#pragma unroll
    for (int i = 0; i < 4; ++i) {
        if (r0 + i < N) {
            float4 v = make_float4(fmaxf(a4[i].x, 0.f), fmaxf(a4[i].y, 0.f),
                                   fmaxf(a4[i].z, 0.f), fmaxf(a4[i].w, 0.f));
            *(float4*)&bA[(r0 + i) * 64 + c0] = v;
            *(float4*)&ob[(size_t)(r0 + i) * 256 + c0] = v;
        }
    }
    __syncthreads();
    {
        float4 acc[4];
#pragma unroll
        for (int i = 0; i < 4; ++i) acc[i] = make_float4(0.f, 0.f, 0.f, 0.f);
        for (int m = 0; m < NPAD; m += 4) {
            float4 sv[4], lv[4];
#pragma unroll
            for (int mm = 0; mm < 4; ++mm) sv[mm] = *(const float4*)&bA[(m + mm) * 64 + c0];
#pragma unroll
            for (int i = 0; i < 4; ++i) lv[i] = *(const float4*)&Ls[(r0 + i) * 64 + m];
#pragma unroll
            for (int i = 0; i < 4; ++i) {
                float l0 = lv[i].x, l1 = lv[i].y, l2 = lv[i].z, l3 = lv[i].w;
                acc[i].x += l0 * sv[0].x; acc[i].y += l0 * sv[0].y; acc[i].z += l0 * sv[0].z; acc[i].w += l0 * sv[0].w;
                acc[i].x += l1 * sv[1].x; acc[i].y += l1 * sv[1].y; acc[i].z += l1 * sv[1].z; acc[i].w += l1 * sv[1].w;
                acc[i].x += l2 * sv[2].x; acc[i].y += l2 * sv[2].y; acc[i].z += l2 * sv[2].z; acc[i].w += l2 * sv[2].w;
                acc[i].x += l3 * sv[3].x; acc[i].y += l3 * sv[3].y; acc[i].z += l3 * sv[3].z; acc[i].w += l3 * sv[3].w;
            }
        }
        float* zb = Z + (size_t)b * N * 256 + sl * 64;
#pragma unroll
        for (int i = 0; i < 4; ++i)
            if (r0 + i < N) *(float4*)&zb[(size_t)(r0 + i) * 256 + c0] = acc[i];
    }
}

// Fused reeb+fps cheb conv. Grid (B, 8): y<4 -> reeb slice y, else fps y-4.
__global__ __launch_bounds__(256) void k_cheb_fused(
        const float* __restrict__ Lr, const float* __restrict__ Vr,
        const float* __restrict__ Wr, const float* __restrict__ br,
        float* __restrict__ outR, float* __restrict__ Zr,
        const float* __restrict__ Lf, const float* __restrict__ Vf,
        const float* __restrict__ Wf, const float* __restrict__ bf,
        float* __restrict__ outP, float* __restrict__ Zf) {
    __shared__ float Ls[64 * 64];
    __shared__ float bA[64 * 64];
    __shared__ float bB[64 * 64];
    __shared__ float Ws[64 * 64];
    int b = blockIdx.x, y = blockIdx.y;
    if (y < 4) cheb_impl<NR>(Lr, Vr, Wr, br, outR, Zr, Ls, bA, bB, Ws, b, y);
    else       cheb_impl<NFPS>(Lf, Vf, Wf, bf, outP, Zf, Ls, bA, bB, Ws, b, y - 4);
}

// ---------------------------------------------------------------------------
// treg_impl<N>: reg += sum((out^T Z)^2) for one (f-tile, g-half) pair.
// ---------------------------------------------------------------------------
template<int N>
__device__ __forceinline__ void treg_impl(const float* __restrict__ out,
                                          const float* __restrict__ Z,
                                          float* __restrict__ reg,
                                          float* zs, float* os, float* red, int y) {
    int b = blockIdx.x;
    int f0 = (y >> 1) * 32;
    int g0 = (y & 1) * 128;
    int t = threadIdx.x;
    for (int q = t; q < N * 128; q += 256) {
        int r = q >> 7, gl = q & 127;
        zs[q] = Z[(size_t)b * N * 256 + r * 256 + g0 + gl];
    }
    for (int q = t; q < N * 32; q += 256) {
        int r = q >> 5, f = q & 31;
        os[q] = out[(size_t)b * N * 256 + r * 256 + f0 + f];
    }
    __syncthreads();
    int fl = t >> 3;           // 0..31
    int gb = (t & 7) * 16;     // 0..112
    float accv[16];
#pragma unroll
    for (int q = 0; q < 16; ++q) accv[q] = 0.f;
    for (int n = 0; n < N; ++n) {
        float a = os[n * 32 + fl];
        const float* zr = zs + n * 128 + gb;
#pragma unroll
        for (int q = 0; q < 16; ++q) accv[q] += a * zr[q];
    }
    float loc = 0.f;
#pragma unroll
    for (int q = 0; q < 16; ++q) loc += accv[q] * accv[q];
    red[t] = loc; __syncthreads();
    for (int st = 128; st > 0; st >>= 1) { if (t < st) red[t] += red[t + st]; __syncthreads(); }
    if (t == 0) atomicAdd(reg, red[0]);
}

// Fused treg + tail. Grid (B, 33): y<16 reeb (regs[1]), y<32 fps (regs[2]),
// y==32 -> per-batch maxpool + MLP -> logits (reuses zs/os as feat/h).
__global__ __launch_bounds__(256) void k_treg_tail(
        const float* __restrict__ outR, const float* __restrict__ Zr,
        const float* __restrict__ outP, const float* __restrict__ Zf,
        const float* __restrict__ fc1_w, const float* __restrict__ fc1_b,
        const float* __restrict__ fc3_w, const float* __restrict__ fc3_b,
        float* __restrict__ regs, float* __restrict__ logits) {
    __shared__ float zs[64 * 128];
    __shared__ float os[64 * 32];
    __shared__ float red[256];
    int y = blockIdx.y;
    if (y < 16) treg_impl<NR>(outR, Zr, regs + 1, zs, os, red, y);
    else if (y < 32) treg_impl<NFPS>(outP, Zf, regs + 2, zs, os, red, y - 16);
    else {
        int b = blockIdx.x, t = threadIdx.x;
        float* feat = zs;          // 512 floats
        float* h = os;             // 256 floats
        float m = -__builtin_inff();
        for (int r = 0; r < NR; ++r) m = fmaxf(m, outR[((size_t)b * NR + r) * 256 + t]);
        feat[t] = m;
        m = -__builtin_inff();
        for (int p = 0; p < NFPS; ++p) m = fmaxf(m, outP[((size_t)b * NFPS + p) * 256 + t]);
        feat[256 + t] = m;
        __syncthreads();
        float a = fc1_b[t];
        for (int i = 0; i < 512; ++i) a += feat[i] * fc1_w[(size_t)i * 256 + t];
        h[t] = fmaxf(a, 0.f);
        __syncthreads();
        if (t < 40) {
            float a2 = fc3_b[t];
            for (int i = 0; i < 256; ++i) a2 += h[i] * fc3_w[(size_t)i * 40 + t];
            logits[(size_t)b * 40 + t] = a2;
        }
    }
}

// ---------------------------------------------------------------------------
extern "C" void kernel_launch(void* const* d_in, const int* in_sizes, int n_in,
                              void* d_out, int out_size, void* d_ws, size_t ws_size,
                              hipStream_t stream) {
    const float* x      = (const float*)d_in[0];
    // d_in[1] (x2) unused by the reference
    const float* L_reeb = (const float*)d_in[2];
    const float* W1     = (const float*)d_in[3];
    const float* b1     = (const float*)d_in[4];
    const float* W_reeb = (const float*)d_in[5];
    const float* b_reeb = (const float*)d_in[6];
    const float* W_fps  = (const float*)d_in[7];
    const float* b_fps  = (const float*)d_in[8];
    const float* fc1_w  = (const float*)d_in[9];
    const float* fc1_b  = (const float*)d_in[10];
    const float* fc3_w  = (const float*)d_in[11];
    const float* fc3_b  = (const float*)d_in[12];
    const int*   sccs   = (const int*)d_in[13];
    const int*   sccs_f = (const int*)d_in[14];

    float* outv = (float*)d_out;          // 32*40 logits
    float* regs = outv + 1280;            // 7 regs

    char* w = (char*)d_ws;
    size_t off = 0;
    auto alloc = [&](size_t bytes) { void* p = w + off; off = (off + bytes + 255) & ~(size_t)255; return p; };
    int*   knn   = (int*)  alloc((size_t)BN * NP * KNN * 4);
    float* xs1   = (float*)alloc((size_t)BN * NP * 7 * 4);
    float* outF  = (float*)alloc((size_t)BN * NP * 64 * 4);
    float* Z1    = (float*)alloc((size_t)BN * NP * 64 * 4);
    float* Vreeb = (float*)alloc((size_t)BN * NR * 64 * 4);
    float* outRb = (float*)alloc((size_t)BN * NR * 256 * 4);
    float* Z2    = (float*)alloc((size_t)BN * NR * 256 * 4);
    float* Vfps  = (float*)alloc((size_t)BN * NFPS * 64 * 4);
    float* Lfps  = (float*)alloc((size_t)BN * NFPS * NFPS * 4);
    float* outP  = (float*)alloc((size_t)BN * NFPS * 256 * 4);
    float* Z3    = (float*)alloc((size_t)BN * NFPS * 256 * 4);

    k_knn<<<dim3(BN, NP / 64), 256, 0, stream>>>(x, knn, xs1,
                                                 fc1_w, fc1_b, fc3_w, fc3_b, regs);
    k_out<<<dim3(BN, 8), 256, 0, stream>>>(x, xs1, knn, W1, b1, outF);
    k_z1v<<<dim3(BN, 256 + 16 + NFPS), 256, 0, stream>>>(outF, knn, sccs, sccs_f,
                                                         Z1, Vreeb, Vfps);
    k_t1_lfps<<<dim3(BN, 3), 256, 0, stream>>>(outF, Z1, Vfps, regs, Lfps);
    k_cheb_fused<<<dim3(BN, 8), 256, 0, stream>>>(L_reeb, Vreeb, W_reeb, b_reeb, outRb, Z2,
                                                  Lfps, Vfps, W_fps, b_fps, outP, Z3);
    k_treg_tail<<<dim3(BN, 33), 256, 0, stream>>>(outRb, Z2, outP, Z3,
                                                  fc1_w, fc1_b, fc3_w, fc3_b, regs, outv);
}

// Round 18
// 388.911 us; speedup vs baseline: 1.2781x; 1.2781x over previous
//
#include <hip/hip_runtime.h>
#include <math.h>

#define BN 32
#define NP 1024
#define KNN 30
#define NR 64
#define NFPS 55

// s = dinv*dinv with dinv = 1/sqrt(30) in f32, matching the reference's
// normalized laplacian (every kNN row-sum is exactly 30).
__device__ __forceinline__ float lap_s() {
    const float dv = 1.0f / sqrtf(30.0f);
    return dv * dv;
}

// Distance with ALL operations IEEE-pinned (contract off): guarantees the
// phase-A value and the phase-C recompute are bit-identical.
__device__ __forceinline__ float dist7(const float4& xiA, const float4& xiB,
                                       float sqi, const float4& ca, const float4& cb) {
#pragma clang fp contract(off)
    float dot = xiA.x * ca.x;
    dot = fmaf(xiA.y, ca.y, dot);
    dot = fmaf(xiA.z, ca.z, dot);
    dot = fmaf(xiA.w, ca.w, dot);
    dot = fmaf(xiB.x, cb.x, dot);
    dot = fmaf(xiB.y, cb.y, dot);
    dot = fmaf(xiB.z, cb.z, dot);
    float r = sqi + cb.w;
    r = r - 2.f * dot;
    return fmaxf(r, 0.f);
}

// ---------------------------------------------------------------------------
// k_knn: 4 waves/row-group split over j, med3 value-only top-30 per wave
// (4-wide j-chunks), per-row 4-way VALUE merge (tie -> lowest wave = jax
// (dist,idx) order), per-wave threshold rescan emits its taken_w indices in
// ascending j (set semantics). xs1 fused via per-wave partials. Block (0,0)
// also does the reg-init work.
// ---------------------------------------------------------------------------
__global__ __launch_bounds__(256) void k_knn(const float* __restrict__ x,
                                             int* __restrict__ knn,
                                             float* __restrict__ xs1,
                                             const float* __restrict__ fc1_w,
                                             const float* __restrict__ fc1_b,
                                             const float* __restrict__ fc3_w,
                                             const float* __restrict__ fc3_b,
                                             float* __restrict__ regs) {
    __shared__ float xls[NP * 8];          // 32768 B: 7 feats + sq in slot 7
    __shared__ float vals[4 * KNN * 64];   // 30720 B (overlaid: init red / ns)
    __shared__ float Tm[4 * 64];           // per-(wave,row) threshold
    __shared__ int   Pk[4 * 64];           // base | (need<<8) | (tk<<16)
    int b = blockIdx.x;
    int t = threadIdx.x;
    int ln = t & 63, wv = t >> 6;

    // ---- folded k_init (one block; uniform branch so barriers are legal) ----
    if (b == 0 && blockIdx.y == 0) {
        float* r1 = vals;        // overlay (vals not yet used)
        float* r2 = vals + 256;
        float s1 = 0.f;
        for (int i = t; i < 512; i += 256) { float v = fc1_w[(size_t)i * 256]; s1 += v * v; }
        float v2 = fc3_w[(size_t)t * 40];
        r1[t] = s1; r2[t] = v2 * v2;
        __syncthreads();
        for (int st = 128; st > 0; st >>= 1) {
            if (t < st) { r1[t] += r1[t + st]; r2[t] += r2[t + st]; }
            __syncthreads();
        }
        if (t == 0) {
            regs[0] = 0.f; regs[1] = 0.f; regs[2] = 0.f;
            regs[3] = r1[0];
            regs[4] = fc1_b[0] * fc1_b[0];
            regs[5] = r2[0];
            regs[6] = fc3_b[0] * fc3_b[0];
        }
        __syncthreads();
    }

    const float* xb = x + (size_t)b * NP * 7;
    for (int q = t; q < NP * 8; q += 256) {
        int r = q >> 3, d = q & 7;
        xls[q] = (d < 7) ? xb[r * 7 + d] : 0.f;
    }
    __syncthreads();
    for (int r = t; r < NP; r += 256) {
        float s = 0.f;
#pragma unroll
        for (int d = 0; d < 7; ++d) { float v = xls[r * 8 + d]; s += v * v; }
        xls[r * 8 + 7] = s;
    }
    __syncthreads();

    int grow = blockIdx.y * 64 + ln;
    float4 xiA = *(const float4*)&xls[grow * 8];
    float4 xiB = *(const float4*)&xls[grow * 8 + 4];
    float sqi = xiB.w;

    // ---- phase A: wave-local branchless value top-30, 4-wide j chunks ----
    float bd[KNN];
#pragma unroll
    for (int q = 0; q < KNN; ++q) bd[q] = __builtin_inff();
    int jbase = wv * 256;
    for (int jc = 0; jc < 256; jc += 4) {
        const float* p = &xls[(jbase + jc) * 8];
        float4 a0 = *(const float4*)(p +  0), b0 = *(const float4*)(p +  4);
        float4 a1 = *(const float4*)(p +  8), b1 = *(const float4*)(p + 12);
        float4 a2 = *(const float4*)(p + 16), b2 = *(const float4*)(p + 20);
        float4 a3 = *(const float4*)(p + 24), b3 = *(const float4*)(p + 28);
        float d0 = dist7(xiA, xiB, sqi, a0, b0);
        float d1 = dist7(xiA, xiB, sqi, a1, b1);
        float d2 = dist7(xiA, xiB, sqi, a2, b2);
        float d3 = dist7(xiA, xiB, sqi, a3, b3);
#pragma unroll
        for (int q = KNN - 1; q >= 1; --q) bd[q] = __builtin_amdgcn_fmed3f(bd[q - 1], d0, bd[q]);
        bd[0] = fminf(bd[0], d0);
#pragma unroll
        for (int q = KNN - 1; q >= 1; --q) bd[q] = __builtin_amdgcn_fmed3f(bd[q - 1], d1, bd[q]);
        bd[0] = fminf(bd[0], d1);
#pragma unroll
        for (int q = KNN - 1; q >= 1; --q) bd[q] = __builtin_amdgcn_fmed3f(bd[q - 1], d2, bd[q]);
        bd[0] = fminf(bd[0], d2);
#pragma unroll
        for (int q = KNN - 1; q >= 1; --q) bd[q] = __builtin_amdgcn_fmed3f(bd[q - 1], d3, bd[q]);
        bd[0] = fminf(bd[0], d3);
    }
#pragma unroll
    for (int q = 0; q < KNN; ++q) vals[wv * (KNN * 64) + q * 64 + ln] = bd[q];
    __syncthreads();

    // ---- merge: one thread per row, 4-way value merge, tie -> lowest wave ----
    if (t < 64) {
        const float inf = __builtin_inff();
        float h0 = vals[0 * 1920 + t];
        float h1 = vals[1 * 1920 + t];
        float h2 = vals[2 * 1920 + t];
        float h3 = vals[3 * 1920 + t];
        int p0 = 0, p1 = 0, p2 = 0, p3 = 0;
        for (int s = 0; s < KNN; ++s) {
            float best = h0; int bw = 0;
            if (h1 < best) { best = h1; bw = 1; }
            if (h2 < best) { best = h2; bw = 2; }
            if (h3 < best) { best = h3; bw = 3; }
            if (bw == 0)      { ++p0; h0 = (p0 < KNN) ? vals[0 * 1920 + p0 * 64 + t] : inf; }
            else if (bw == 1) { ++p1; h1 = (p1 < KNN) ? vals[1 * 1920 + p1 * 64 + t] : inf; }
            else if (bw == 2) { ++p2; h2 = (p2 < KNN) ? vals[2 * 1920 + p2 * 64 + t] : inf; }
            else              { ++p3; h3 = (p3 < KNN) ? vals[3 * 1920 + p3 * 64 + t] : inf; }
        }
        int bacc = 0;
        int tks[4] = {p0, p1, p2, p3};
#pragma unroll
        for (int w = 0; w < 4; ++w) {
            int tk = tks[w];
            float T; int need;
            if (tk == 0) { T = -__builtin_inff(); need = 0; }
            else {
                T = vals[w * 1920 + (tk - 1) * 64 + t];
                need = 1;
                for (int q = tk - 2; q >= 0; --q) {
                    if (vals[w * 1920 + q * 64 + t] == T) ++need; else break;
                }
            }
            Tm[w * 64 + t] = T;
            Pk[w * 64 + t] = bacc | (need << 8) | (tk << 16);
            bacc += tk;
        }
    }
    __syncthreads();

    // ---- phase C: per-wave threshold rescan (4-wide chunks), emit + ns ----
    float Tw = Tm[wv * 64 + ln];
    int pk = Pk[wv * 64 + ln];
    int base = pk & 255, need = (pk >> 8) & 255, tk = pk >> 16;
    int* kout = knn + ((size_t)b * NP + grow) * KNN;
    float n0 = 0.f, n1 = 0.f, n2 = 0.f, n3 = 0.f, n4 = 0.f, n5 = 0.f, n6 = 0.f;
    int cs = 0, ct = 0;
    for (int jc = 0; jc < 256; jc += 4) {
        const float* p = &xls[(jbase + jc) * 8];
        float4 a0 = *(const float4*)(p +  0), b0 = *(const float4*)(p +  4);
        float4 a1 = *(const float4*)(p +  8), b1 = *(const float4*)(p + 12);
        float4 a2 = *(const float4*)(p + 16), b2 = *(const float4*)(p + 20);
        float4 a3 = *(const float4*)(p + 24), b3 = *(const float4*)(p + 28);
        float d0 = dist7(xiA, xiB, sqi, a0, b0);
        float d1 = dist7(xiA, xiB, sqi, a1, b1);
        float d2 = dist7(xiA, xiB, sqi, a2, b2);
        float d3 = dist7(xiA, xiB, sqi, a3, b3);
#pragma unroll
        for (int u = 0; u < 4; ++u) {
            float dist = (u == 0) ? d0 : (u == 1) ? d1 : (u == 2) ? d2 : d3;
            const float4& ca = (u == 0) ? a0 : (u == 1) ? a1 : (u == 2) ? a2 : a3;
            const float4& cb = (u == 0) ? b0 : (u == 1) ? b1 : (u == 2) ? b2 : b3;
            bool lt = dist < Tw;
            bool eq = (dist == Tw) && (ct < need);
            if ((lt || eq) && (cs + ct < tk)) {
                kout[base + cs + ct] = jbase + jc + u;
                cs += lt ? 1 : 0;
                ct += eq ? 1 : 0;
                n0 += ca.x; n1 += ca.y; n2 += ca.z; n3 += ca.w;
                n4 += cb.x; n5 += cb.y; n6 += cb.z;
            }
        }
    }
    for (int q = cs + ct; q < tk; ++q) kout[base + q] = grow;  // safety net
    float* nsb = vals;
    nsb[wv * 448 + 0 * 64 + ln] = n0;
    nsb[wv * 448 + 1 * 64 + ln] = n1;
    nsb[wv * 448 + 2 * 64 + ln] = n2;
    nsb[wv * 448 + 3 * 64 + ln] = n3;
    nsb[wv * 448 + 4 * 64 + ln] = n4;
    nsb[wv * 448 + 5 * 64 + ln] = n5;
    nsb[wv * 448 + 6 * 64 + ln] = n6;
    __syncthreads();
    for (int u = t; u < 448; u += 256) {
        int d = u >> 6, rl = u & 63;
        float tot = nsb[d * 64 + rl] + nsb[448 + d * 64 + rl]
                  + nsb[896 + d * 64 + rl] + nsb[1344 + d * 64 + rl];
        int gr = blockIdx.y * 64 + rl;
        xs1[((size_t)b * NP + gr) * 7 + d] = xls[gr * 8 + d] - lap_s() * tot;
    }
}

// ---------------------------------------------------------------------------
// k_out: xs2 = 2 L xs1 - x, then out = relu([x|xs1|xs2] @ W1 + b1), (B,N,64).
// ---------------------------------------------------------------------------
__global__ __launch_bounds__(256) void k_out(const float* __restrict__ x,
                                             const float* __restrict__ xs1,
                                             const int* __restrict__ knn,
                                             const float* __restrict__ W1,
                                             const float* __restrict__ b1,
                                             float* __restrict__ out) {
    __shared__ float x1s[NP * 7];    // xs1 for ALL rows (neighbor gathers)
    __shared__ float x0s[128 * 7];   // x for this block's rows only
    __shared__ float fr[128 * 21];
    __shared__ float W1s[21 * 64];
    __shared__ float b1s[64];
    int b = blockIdx.x;
    int rbase = blockIdx.y * 128;
    int t = threadIdx.x;
    for (int q = t; q < NP * 7; q += 256) x1s[q] = xs1[(size_t)b * NP * 7 + q];
    for (int q = t; q < 128 * 7; q += 256) x0s[q] = x[(size_t)b * NP * 7 + (size_t)rbase * 7 + q];
    for (int q = t; q < 21 * 64; q += 256) W1s[q] = W1[q];
    if (t < 64) b1s[t] = b1[t];
    __syncthreads();
    if (t < 128) {
        int i = rbase + t;
        float f[21];
#pragma unroll
        for (int d = 0; d < 7; ++d) { f[d] = x0s[t * 7 + d]; f[7 + d] = x1s[i * 7 + d]; }
        float ns[7] = {0.f, 0.f, 0.f, 0.f, 0.f, 0.f, 0.f};
        const int* kn = knn + ((size_t)b * NP + i) * KNN;
        for (int q = 0; q < KNN; ++q) {
            int j = kn[q];
#pragma unroll
            for (int d = 0; d < 7; ++d) ns[d] += x1s[j * 7 + d];
        }
        const float s = lap_s();
#pragma unroll
        for (int d = 0; d < 7; ++d) f[14 + d] = 2.f * (f[7 + d] - s * ns[d]) - f[d];
#pragma unroll
        for (int d = 0; d < 21; ++d) fr[t * 21 + d] = f[d];
    }
    __syncthreads();
    int o = t & 63, g = t >> 6;
    for (int m = 0; m < 32; ++m) {
        int r = g * 32 + m;
        float acc = b1s[o];
#pragma unroll
        for (int d = 0; d < 21; ++d) acc += fr[r * 21 + d] * W1s[d * 64 + o];
        out[((size_t)b * NP + rbase + r) * 64 + o] = fmaxf(acc, 0.f);
    }
}

// ---------------------------------------------------------------------------
// k_z1v: fused Z1 = L@out gather + segment-max pools. Grid (B, 256+16+55):
//   y<256  -> Z1 rows y*4..y*4+3
//   y<272  -> V_reeb rows (y-256)*4.. (16-segment max)
//   else   -> V_fps row p=y-272 (1024-segment max)
// ---------------------------------------------------------------------------
__global__ __launch_bounds__(256) void k_z1v(const float* __restrict__ out,
                                             const int* __restrict__ knn,
                                             const int* __restrict__ sccs,
                                             const int* __restrict__ sccs_fps,
                                             float* __restrict__ Z1,
                                             float* __restrict__ Vr,
                                             float* __restrict__ Vf) {
    __shared__ int idxs[1024];
    __shared__ float red[256];
    int b = blockIdx.x, y = blockIdx.y;
    int t = threadIdx.x;
    const float* ob = out + (size_t)b * NP * 64;
    if (y < 256) {
        int i = y * 4 + (t >> 6);
        int f = t & 63;
        const int* kn = knn + ((size_t)b * NP + i) * KNN;
        float sum = 0.f;
        for (int q = 0; q < KNN; ++q) sum += ob[(size_t)kn[q] * 64 + f];
        Z1[((size_t)b * NP + i) * 64 + f] = ob[(size_t)i * 64 + f] - lap_s() * sum;
    } else if (y < 272) {
        int r = (y - 256) * 4 + (t >> 6);
        int f = t & 63;
        const int* sc = sccs + ((size_t)b * NR + r) * 16;
        float m = -__builtin_inff();
        for (int q = 0; q < 16; ++q) m = fmaxf(m, ob[(size_t)sc[q] * 64 + f]);
        Vr[((size_t)b * NR + r) * 64 + f] = m;
    } else {
        int p = y - 272;
        const int* sp = sccs_fps + ((size_t)b * NFPS + p) * 1024;
        for (int q = t; q < 1024; q += 256) idxs[q] = sp[q];
        __syncthreads();
        int f = t & 63, sc = t >> 6;
        float m = -__builtin_inff();
        for (int s = sc; s < 1024; s += 4) m = fmaxf(m, ob[(size_t)idxs[s] * 64 + f]);
        red[t] = m; __syncthreads();
        if (sc == 0) {
            m = fmaxf(fmaxf(red[f], red[64 + f]), fmaxf(red[128 + f], red[192 + f]));
            Vf[((size_t)b * NFPS + p) * 64 + f] = m;
        }
    }
}

// ---------------------------------------------------------------------------
// k_t1_lfps: fused (independent) narrow kernels. Grid (B, 3):
//   y<2  -> reg1 += sum((out^T Z1)^2) for f-half y (R10-proven t1 body;
//           do NOT widen -- the (B,8)/128-trip variant spilled to scratch)
//   y==2 -> L_fps build from V_fps (R10-proven lfps body)
// ---------------------------------------------------------------------------
__global__ __launch_bounds__(256) void k_t1_lfps(const float* __restrict__ out,
                                                 const float* __restrict__ Z1,
                                                 const float* __restrict__ Vfps,
                                                 float* __restrict__ regs,
                                                 float* __restrict__ Lf) {
    __shared__ float buf[8448];   // 33 KB union of both branches
    int b = blockIdx.x, y = blockIdx.y;
    int t = threadIdx.x;
    if (y < 2) {
        float* os = buf;              // 64*64
        float* zs = buf + 4096;       // 64*64
        float* red = buf + 8192;      // 256
        int f0 = y * 32;
        int fl = t >> 3;          // 0..31
        int gb = (t & 7) * 8;     // 0..56
        float acc[8];
#pragma unroll
        for (int q = 0; q < 8; ++q) acc[q] = 0.f;
        for (int c = 0; c < 16; ++c) {
            const float* ob = out + ((size_t)b * NP + c * 64) * 64;
            const float* zb = Z1 + ((size_t)b * NP + c * 64) * 64;
            for (int q = t; q < 64 * 64; q += 256) { os[q] = ob[q]; zs[q] = zb[q]; }
            __syncthreads();
            for (int n = 0; n < 64; ++n) {
                float a = os[n * 64 + f0 + fl];
#pragma unroll
                for (int q = 0; q < 8; ++q) acc[q] += a * zs[n * 64 + gb + q];
            }
            __syncthreads();
        }
        float loc = 0.f;
#pragma unroll
        for (int q = 0; q < 8; ++q) loc += acc[q] * acc[q];
        red[t] = loc; __syncthreads();
        for (int st = 128; st > 0; st >>= 1) { if (t < st) red[t] += red[t + st]; __syncthreads(); }
        if (t == 0) atomicAdd(&regs[0], red[0]);
    } else {
        float* Vs = buf;                    // 55*64 = 3520
        float* sq = buf + 3520;             // 55 (pad to 3584)
        float* dist = buf + 3584;           // 55*55 = 3025
        float* dinv = buf + 6609;           // 55
        for (int q = t; q < NFPS * 64; q += 256) Vs[q] = Vfps[(size_t)b * NFPS * 64 + q];
        __syncthreads();
        if (t < NFPS) {
            float s = 0.f;
            for (int f = 0; f < 64; ++f) { float v = Vs[t * 64 + f]; s += v * v; }
            sq[t] = s;
        }
        __syncthreads();
        for (int q = t; q < NFPS * NFPS; q += 256) {
            int i = q / NFPS, j = q % NFPS;
            float dot = 0.f;
            for (int f = 0; f < 64; ++f) dot += Vs[i * 64 + f] * Vs[j * 64 + f];
            dist[q] = fmaxf(sq[i] + sq[j] - 2.f * dot, 0.f);
        }
        __syncthreads();
        if (t < NFPS) {
            float s = 0.f;
            for (int j = 0; j < NFPS; ++j) s += dist[t * NFPS + j];
            dinv[t] = (s > 0.f) ? 1.0f / sqrtf(fmaxf(s, 1e-12f)) : 0.f;
        }
        __syncthreads();
        for (int q = t; q < NFPS * NFPS; q += 256) {
            int i = q / NFPS, j = q % NFPS;
            Lf[(size_t)b * NFPS * NFPS + q] = ((i == j) ? 1.f : 0.f) - dist[q] * dinv[i] * dinv[j];
        }
    }
}

// ---------------------------------------------------------------------------
// cheb_impl<N>: K=6 Chebyshev conv + relu + Z = L @ out, one batch, one
// 64-wide output-column slice. Register-tiled 4x4 per thread, float4 LDS
// reads both operands. Pad rows/cols zeroed so N=55 needs no read guards.
// m-loops pinned to unroll 2: the R17 container's compiler fully unrolled
// them (VGPR 132->256, LDS conflicts 0->3e6, cheb 92->150 us). Explicit
// unroll factors are the only robust defense against toolchain drift.
// ---------------------------------------------------------------------------
template<int N>
__device__ __forceinline__ void cheb_impl(const float* __restrict__ L,
                                          const float* __restrict__ V,
                                          const float* __restrict__ W,
                                          const float* __restrict__ bias,
                                          float* __restrict__ out,
                                          float* __restrict__ Z,
                                          float* Ls, float* bA, float* bB, float* Ws,
                                          int b, int sl) {
    constexpr int NPAD = (N + 3) & ~3;   // 64 or 56
    int t = threadIdx.x;
    int c0 = (t & 15) * 4;               // 0..60
    int r0 = (t >> 4) * 4;               // 0..60

    for (int q = t; q < 64 * 64; q += 256) { Ls[q] = 0.f; bA[q] = 0.f; bB[q] = 0.f; }
    __syncthreads();
    for (int q = t; q < N * N; q += 256) {
        int r = q / N, m = q % N;
        Ls[r * 64 + m] = L[(size_t)b * N * N + q];
    }
    for (int q = t; q < N * 64; q += 256) bA[q] = V[(size_t)b * N * 64 + q];
    {
        const float* Wk = W + sl * 64;
        for (int q = t; q < 64 * 64; q += 256) Ws[q] = Wk[(q >> 6) * 256 + (q & 63)];
    }
    float4 a4[4];
    {
        float4 bv = *(const float4*)&bias[sl * 64 + c0];
#pragma unroll
        for (int i = 0; i < 4; ++i) a4[i] = bv;
    }
    __syncthreads();

    auto accum = [&](const float* xb) {
#pragma unroll 2
        for (int m = 0; m < 64; m += 4) {
            float4 xv[4], wv[4];
#pragma unroll
            for (int i = 0; i < 4; ++i) xv[i] = *(const float4*)&xb[(r0 + i) * 64 + m];
#pragma unroll
            for (int mm = 0; mm < 4; ++mm) wv[mm] = *(const float4*)&Ws[(m + mm) * 64 + c0];
#pragma unroll
            for (int i = 0; i < 4; ++i) {
                float xi0 = xv[i].x, xi1 = xv[i].y, xi2 = xv[i].z, xi3 = xv[i].w;
                a4[i].x += xi0 * wv[0].x; a4[i].y += xi0 * wv[0].y; a4[i].z += xi0 * wv[0].z; a4[i].w += xi0 * wv[0].w;
                a4[i].x += xi1 * wv[1].x; a4[i].y += xi1 * wv[1].y; a4[i].z += xi1 * wv[1].z; a4[i].w += xi1 * wv[1].w;
                a4[i].x += xi2 * wv[2].x; a4[i].y += xi2 * wv[2].y; a4[i].z += xi2 * wv[2].z; a4[i].w += xi2 * wv[2].w;
                a4[i].x += xi3 * wv[3].x; a4[i].y += xi3 * wv[3].y; a4[i].z += xi3 * wv[3].z; a4[i].w += xi3 * wv[3].w;
            }
        }
    };
    auto chebmm = [&](const float* src, float* dst, bool first) {
        float4 acc[4];
#pragma unroll
        for (int i = 0; i < 4; ++i) acc[i] = make_float4(0.f, 0.f, 0.f, 0.f);
#pragma unroll 2
        for (int m = 0; m < NPAD; m += 4) {
            float4 sv[4], lv[4];
#pragma unroll
            for (int mm = 0; mm < 4; ++mm) sv[mm] = *(const float4*)&src[(m + mm) * 64 + c0];
#pragma unroll
            for (int i = 0; i < 4; ++i) lv[i] = *(const float4*)&Ls[(r0 + i) * 64 + m];
#pragma unroll
            for (int i = 0; i < 4; ++i) {
                float l0 = lv[i].x, l1 = lv[i].y, l2 = lv[i].z, l3 = lv[i].w;
                acc[i].x += l0 * sv[0].x; acc[i].y += l0 * sv[0].y; acc[i].z += l0 * sv[0].z; acc[i].w += l0 * sv[0].w;
                acc[i].x += l1 * sv[1].x; acc[i].y += l1 * sv[1].y; acc[i].z += l1 * sv[1].z; acc[i].w += l1 * sv[1].w;
                acc[i].x += l2 * sv[2].x; acc[i].y += l2 * sv[2].y; acc[i].z += l2 * sv[2].z; acc[i].w += l2 * sv[2].w;
                acc[i].x += l3 * sv[3].x; acc[i].y += l3 * sv[3].y; acc[i].z += l3 * sv[3].z; acc[i].w += l3 * sv[3].w;
            }
        }
#pragma unroll
        for (int i = 0; i < 4; ++i) {
            if (r0 + i < N) {
                float4* d = (float4*)&dst[(r0 + i) * 64 + c0];
                if (first) *d = acc[i];
                else {
                    float4 od = *d;
                    *d = make_float4(2.f * acc[i].x - od.x, 2.f * acc[i].y - od.y,
                                     2.f * acc[i].z - od.z, 2.f * acc[i].w - od.w);
                }
            }
        }
    };
    auto loadW = [&](int k) {
        const float* Wk = W + (size_t)k * 64 * 256 + sl * 64;
        for (int q = t; q < 64 * 64; q += 256) Ws[q] = Wk[(q >> 6) * 256 + (q & 63)];
    };

    accum(bA);                 __syncthreads();
    chebmm(bA, bB, true);      loadW(1);  __syncthreads();
    accum(bB);                 __syncthreads();
    chebmm(bB, bA, false);     loadW(2);  __syncthreads();
    accum(bA);                 __syncthreads();
    chebmm(bA, bB, false);     loadW(3);  __syncthreads();
    accum(bB);                 __syncthreads();
    chebmm(bB, bA, false);     loadW(4);  __syncthreads();
    accum(bA);                 __syncthreads();
    chebmm(bA, bB, false);     loadW(5);  __syncthreads();
    accum(bB);                 __syncthreads();

    float* ob = out + (size_t)b * N * 256 + sl * 64;
#pragma unroll
    for (int i = 0; i < 4; ++i) {
        if (r0 + i < N) {
            float4 v = make_float4(fmaxf(a4[i].x, 0.f), fmaxf(a4[i].y, 0.f),
                                   fmaxf(a4[i].z, 0.f), fmaxf(a4[i].w, 0.f));
            *(float4*)&bA[(r0 + i) * 64 + c0] = v;
            *(float4*)&ob[(size_t)(r0 + i) * 256 + c0] = v;
        }
    }
    __syncthreads();
    {
        float4 acc[4];
#pragma unroll
        for (int i = 0; i < 4; ++i) acc[i] = make_float4(0.f, 0.f, 0.f, 0.f);
#pragma unroll 2
        for (int m = 0; m < NPAD; m += 4) {
            float4 sv[4], lv[4];
#pragma unroll
            for (int mm = 0; mm < 4; ++mm) sv[mm] = *(const float4*)&bA[(m + mm) * 64 + c0];
#pragma unroll
            for (int i = 0; i < 4; ++i) lv[i] = *(const float4*)&Ls[(r0 + i) * 64 + m];
#pragma unroll
            for (int i = 0; i < 4; ++i) {
                float l0 = lv[i].x, l1 = lv[i].y, l2 = lv[i].z, l3 = lv[i].w;
                acc[i].x += l0 * sv[0].x; acc[i].y += l0 * sv[0].y; acc[i].z += l0 * sv[0].z; acc[i].w += l0 * sv[0].w;
                acc[i].x += l1 * sv[1].x; acc[i].y += l1 * sv[1].y; acc[i].z += l1 * sv[1].z; acc[i].w += l1 * sv[1].w;
                acc[i].x += l2 * sv[2].x; acc[i].y += l2 * sv[2].y; acc[i].z += l2 * sv[2].z; acc[i].w += l2 * sv[2].w;
                acc[i].x += l3 * sv[3].x; acc[i].y += l3 * sv[3].y; acc[i].z += l3 * sv[3].z; acc[i].w += l3 * sv[3].w;
            }
        }
        float* zb = Z + (size_t)b * N * 256 + sl * 64;
#pragma unroll
        for (int i = 0; i < 4; ++i)
            if (r0 + i < N) *(float4*)&zb[(size_t)(r0 + i) * 256 + c0] = acc[i];
    }
}

// Fused reeb+fps cheb conv. Grid (B, 8): y<4 -> reeb slice y, else fps y-4.
__global__ __launch_bounds__(256) void k_cheb_fused(
        const float* __restrict__ Lr, const float* __restrict__ Vr,
        const float* __restrict__ Wr, const float* __restrict__ br,
        float* __restrict__ outR, float* __restrict__ Zr,
        const float* __restrict__ Lf, const float* __restrict__ Vf,
        const float* __restrict__ Wf, const float* __restrict__ bf,
        float* __restrict__ outP, float* __restrict__ Zf) {
    __shared__ float Ls[64 * 64];
    __shared__ float bA[64 * 64];
    __shared__ float bB[64 * 64];
    __shared__ float Ws[64 * 64];
    int b = blockIdx.x, y = blockIdx.y;
    if (y < 4) cheb_impl<NR>(Lr, Vr, Wr, br, outR, Zr, Ls, bA, bB, Ws, b, y);
    else       cheb_impl<NFPS>(Lf, Vf, Wf, bf, outP, Zf, Ls, bA, bB, Ws, b, y - 4);
}

// ---------------------------------------------------------------------------
// treg_impl<N>: reg += sum((out^T Z)^2) for one (f-tile, g-half) pair.
// ---------------------------------------------------------------------------
template<int N>
__device__ __forceinline__ void treg_impl(const float* __restrict__ out,
                                          const float* __restrict__ Z,
                                          float* __restrict__ reg,
                                          float* zs, float* os, float* red, int y) {
    int b = blockIdx.x;
    int f0 = (y >> 1) * 32;
    int g0 = (y & 1) * 128;
    int t = threadIdx.x;
    for (int q = t; q < N * 128; q += 256) {
        int r = q >> 7, gl = q & 127;
        zs[q] = Z[(size_t)b * N * 256 + r * 256 + g0 + gl];
    }
    for (int q = t; q < N * 32; q += 256) {
        int r = q >> 5, f = q & 31;
        os[q] = out[(size_t)b * N * 256 + r * 256 + f0 + f];
    }
    __syncthreads();
    int fl = t >> 3;           // 0..31
    int gb = (t & 7) * 16;     // 0..112
    float accv[16];
#pragma unroll
    for (int q = 0; q < 16; ++q) accv[q] = 0.f;
    for (int n = 0; n < N; ++n) {
        float a = os[n * 32 + fl];
        const float* zr = zs + n * 128 + gb;
#pragma unroll
        for (int q = 0; q < 16; ++q) accv[q] += a * zr[q];
    }
    float loc = 0.f;
#pragma unroll
    for (int q = 0; q < 16; ++q) loc += accv[q] * accv[q];
    red[t] = loc; __syncthreads();
    for (int st = 128; st > 0; st >>= 1) { if (t < st) red[t] += red[t + st]; __syncthreads(); }
    if (t == 0) atomicAdd(reg, red[0]);
}

// Fused treg + tail. Grid (B, 33): y<16 reeb (regs[1]), y<32 fps (regs[2]),
// y==32 -> per-batch maxpool + MLP -> logits (reuses zs/os as feat/h).
__global__ __launch_bounds__(256) void k_treg_tail(
        const float* __restrict__ outR, const float* __restrict__ Zr,
        const float* __restrict__ outP, const float* __restrict__ Zf,
        const float* __restrict__ fc1_w, const float* __restrict__ fc1_b,
        const float* __restrict__ fc3_w, const float* __restrict__ fc3_b,
        float* __restrict__ regs, float* __restrict__ logits) {
    __shared__ float zs[64 * 128];
    __shared__ float os[64 * 32];
    __shared__ float red[256];
    int y = blockIdx.y;
    if (y < 16) treg_impl<NR>(outR, Zr, regs + 1, zs, os, red, y);
    else if (y < 32) treg_impl<NFPS>(outP, Zf, regs + 2, zs, os, red, y - 16);
    else {
        int b = blockIdx.x, t = threadIdx.x;
        float* feat = zs;          // 512 floats
        float* h = os;             // 256 floats
        float m = -__builtin_inff();
        for (int r = 0; r < NR; ++r) m = fmaxf(m, outR[((size_t)b * NR + r) * 256 + t]);
        feat[t] = m;
        m = -__builtin_inff();
        for (int p = 0; p < NFPS; ++p) m = fmaxf(m, outP[((size_t)b * NFPS + p) * 256 + t]);
        feat[256 + t] = m;
        __syncthreads();
        float a = fc1_b[t];
        for (int i = 0; i < 512; ++i) a += feat[i] * fc1_w[(size_t)i * 256 + t];
        h[t] = fmaxf(a, 0.f);
        __syncthreads();
        if (t < 40) {
            float a2 = fc3_b[t];
            for (int i = 0; i < 256; ++i) a2 += h[i] * fc3_w[(size_t)i * 40 + t];
            logits[(size_t)b * 40 + t] = a2;
        }
    }
}

// ---------------------------------------------------------------------------
extern "C" void kernel_launch(void* const* d_in, const int* in_sizes, int n_in,
                              void* d_out, int out_size, void* d_ws, size_t ws_size,
                              hipStream_t stream) {
    const float* x      = (const float*)d_in[0];
    // d_in[1] (x2) unused by the reference
    const float* L_reeb = (const float*)d_in[2];
    const float* W1     = (const float*)d_in[3];
    const float* b1     = (const float*)d_in[4];
    const float* W_reeb = (const float*)d_in[5];
    const float* b_reeb = (const float*)d_in[6];
    const float* W_fps  = (const float*)d_in[7];
    const float* b_fps  = (const float*)d_in[8];
    const float* fc1_w  = (const float*)d_in[9];
    const float* fc1_b  = (const float*)d_in[10];
    const float* fc3_w  = (const float*)d_in[11];
    const float* fc3_b  = (const float*)d_in[12];
    const int*   sccs   = (const int*)d_in[13];
    const int*   sccs_f = (const int*)d_in[14];

    float* outv = (float*)d_out;          // 32*40 logits
    float* regs = outv + 1280;            // 7 regs

    char* w = (char*)d_ws;
    size_t off = 0;
    auto alloc = [&](size_t bytes) { void* p = w + off; off = (off + bytes + 255) & ~(size_t)255; return p; };
    int*   knn   = (int*)  alloc((size_t)BN * NP * KNN * 4);
    float* xs1   = (float*)alloc((size_t)BN * NP * 7 * 4);
    float* outF  = (float*)alloc((size_t)BN * NP * 64 * 4);
    float* Z1    = (float*)alloc((size_t)BN * NP * 64 * 4);
    float* Vreeb = (float*)alloc((size_t)BN * NR * 64 * 4);
    float* outRb = (float*)alloc((size_t)BN * NR * 256 * 4);
    float* Z2    = (float*)alloc((size_t)BN * NR * 256 * 4);
    float* Vfps  = (float*)alloc((size_t)BN * NFPS * 64 * 4);
    float* Lfps  = (float*)alloc((size_t)BN * NFPS * NFPS * 4);
    float* outP  = (float*)alloc((size_t)BN * NFPS * 256 * 4);
    float* Z3    = (float*)alloc((size_t)BN * NFPS * 256 * 4);

    k_knn<<<dim3(BN, NP / 64), 256, 0, stream>>>(x, knn, xs1,
                                                 fc1_w, fc1_b, fc3_w, fc3_b, regs);
    k_out<<<dim3(BN, 8), 256, 0, stream>>>(x, xs1, knn, W1, b1, outF);
    k_z1v<<<dim3(BN, 256 + 16 + NFPS), 256, 0, stream>>>(outF, knn, sccs, sccs_f,
                                                         Z1, Vreeb, Vfps);
    k_t1_lfps<<<dim3(BN, 3), 256, 0, stream>>>(outF, Z1, Vfps, regs, Lfps);
    k_cheb_fused<<<dim3(BN, 8), 256, 0, stream>>>(L_reeb, Vreeb, W_reeb, b_reeb, outRb, Z2,
                                                  Lfps, Vfps, W_fps, b_fps, outP, Z3);
    k_treg_tail<<<dim3(BN, 33), 256, 0, stream>>>(outRb, Z2, outP, Z3,
                                                  fc1_w, fc1_b, fc3_w, fc3_b, regs, outv);
}